// Round 2
// baseline (508.622 us; speedup 1.0000x reference)
//
#include <hip/hip_runtime.h>
#include <stdint.h>

// WeightedNeighborSampler — reproduce jax.random.categorical(key(42), log(w))
// exactly.
//   RNG: threefry2x32, key (0,42), partitionable counter mode (JAX >= 0.4.30
//   default). For 32-bit output bits, JAX's _threefry_random_bits_partitionable
//   XOR-FOLDS the two output words:  bits[i] = out0 ^ out1 of
//   encrypt(x0=counts_hi=0, x1=counts_lo=i).       <-- fix vs round 0 (used out1)
//   u = bitcast((bits>>9)|0x3f800000)-1.0f, ==0 -> FLT_MIN
//   z_d = log(w_d) + (-log(-log(u_d))) in f64 (exact ranking; only the
//   reference's own f32 rounding could flip a near-tie, P ~ 1e-7/row)
//   argmax over d=0..127 first-occurrence; gather adj_info[ids[b]][argmax].
// Fallback if this still mismatches: legacy (non-partitionable) pairing
//   bits[i] = out0 of enc(i, i+N/2) for i<N/2, out1 of enc(i-N/2, i) else.

#define MAXDEG 128

__device__ __forceinline__ void tf_round(uint32_t& x0, uint32_t& x1, int r) {
  x0 += x1;
  x1 = (x1 << r) | (x1 >> (32 - r));
  x1 ^= x0;
}

// threefry2x32, key (0, 42), counter (0, i); returns out0 ^ out1 (JAX
// partitionable 32-bit fold).
__device__ __forceinline__ uint32_t tf_bits(uint32_t i) {
  const uint32_t ks0 = 0u;
  const uint32_t ks1 = 42u;
  const uint32_t ks2 = 0x1BD11BF0u;  // 0 ^ 42 ^ 0x1BD11BDA
  uint32_t x0 = ks0;       // counts_hi(=0) + ks0
  uint32_t x1 = i + ks1;   // counts_lo(=i) + ks1
  tf_round(x0, x1, 13); tf_round(x0, x1, 15); tf_round(x0, x1, 26); tf_round(x0, x1, 6);
  x0 += ks1; x1 += ks2 + 1u;
  tf_round(x0, x1, 17); tf_round(x0, x1, 29); tf_round(x0, x1, 16); tf_round(x0, x1, 24);
  x0 += ks2; x1 += ks0 + 2u;
  tf_round(x0, x1, 13); tf_round(x0, x1, 15); tf_round(x0, x1, 26); tf_round(x0, x1, 6);
  x0 += ks0; x1 += ks1 + 3u;
  tf_round(x0, x1, 17); tf_round(x0, x1, 29); tf_round(x0, x1, 16); tf_round(x0, x1, 24);
  x0 += ks1; x1 += ks2 + 4u;
  tf_round(x0, x1, 13); tf_round(x0, x1, 15); tf_round(x0, x1, 26); tf_round(x0, x1, 6);
  x0 += ks2; x1 += ks0 + 5u;  // final key injection
  return x0 ^ x1;             // XOR-fold of the 64-bit block to 32 bits
}

// JAX uniform(minval=tiny, maxval=1) from 32 random bits, then gumbel in f64.
__device__ __forceinline__ double gumbel_from_bits(uint32_t bits) {
  uint32_t fb = (bits >> 9) | 0x3f800000u;
  float f = __uint_as_float(fb) - 1.0f;     // [0, 1), multiples of 2^-23
  if (f == 0.0f) f = 1.17549435e-38f;       // max(tiny, f*1+tiny) == this
  double u = (double)f;
  return -log(-log(u));
}

__global__ __launch_bounds__(256) void wns_kernel(
    const float* __restrict__ adj_weight,
    const int* __restrict__ adj_info,
    const int* __restrict__ ids,
    int* __restrict__ out,
    int batch, int nsamp) {
  const int lane = threadIdx.x & 63;
  const int waveInBlk = threadIdx.x >> 6;
  const long long row = (long long)blockIdx.x * 4 + waveInBlk;  // row = s*batch + b
  const long long rows = (long long)nsamp * batch;
  if (row >= rows) return;

  const int s = (int)(row / batch);
  const int b = (int)(row % batch);
  const long long nid = (long long)ids[b];
  const float* wrow = adj_weight + nid * MAXDEG;

  // flat gumbel index base for this row: ((s*batch)+b)*128
  const uint32_t base = (uint32_t)(row * MAXDEG);

  // lane-local: two neighbor slots d and d+64
  const int d0 = lane;
  double bestZ = log((double)wrow[d0]) + gumbel_from_bits(tf_bits(base + (uint32_t)d0));
  int bestD = d0;
  const int d1 = lane + 64;
  double z1 = log((double)wrow[d1]) + gumbel_from_bits(tf_bits(base + (uint32_t)d1));
  if (z1 > bestZ) { bestZ = z1; bestD = d1; }  // d1 > d0: strict > keeps first-max

  // wave argmax reduce (max z, min d on exact ties == jnp.argmax first-occurrence)
  #pragma unroll
  for (int m = 1; m < 64; m <<= 1) {
    double oz = __shfl_xor(bestZ, m);
    int od = __shfl_xor(bestD, m);
    if (oz > bestZ || (oz == bestZ && od < bestD)) { bestZ = oz; bestD = od; }
  }

  if (lane == 0) {
    // res[b][s] = adj_info[ids[b]][argmax]
    out[(long long)b * nsamp + s] = adj_info[nid * MAXDEG + bestD];
  }
}

extern "C" void kernel_launch(void* const* d_in, const int* in_sizes, int n_in,
                              void* d_out, int out_size, void* d_ws, size_t ws_size,
                              hipStream_t stream) {
  const float* adj_weight = (const float*)d_in[0];
  const int* adj_info = (const int*)d_in[1];
  const int* ids = (const int*)d_in[2];      // harness materializes ints as int32
  int batch = in_sizes[2];
  int nsamp = out_size / batch;              // 25
  long long rows = (long long)nsamp * batch; // 409600 waves, 4 waves/block
  int blocks = (int)((rows + 3) / 4);
  wns_kernel<<<blocks, 256, 0, stream>>>(adj_weight, adj_info, ids,
                                         (int*)d_out, batch, nsamp);
}

// Round 3
// 183.702 us; speedup vs baseline: 2.7687x; 2.7687x over previous
//
#include <hip/hip_runtime.h>
#include <stdint.h>

// WeightedNeighborSampler — exact reproduction of
// jax.random.categorical(key(42), log(w)) (partitionable threefry, XOR-fold).
//
// Round-3 optimization (round 2 passed, absmax 0, 508us, VALUBusy 101%):
//  - one wave per batch row b, looping the 25 samples: log(w) and the
//    adj_weight/adj_info rows are loaded/computed once, not 25x.
//  - f32 fast path for the Gumbel ranking using hardware v_log_f32; a wave
//    ballot counts candidates within 3e-4 of the max. If exactly one, the
//    f32 argmax provably equals the f64 argmax (|z32-z64| <= ~6e-5).
//    Otherwise (P ~ 2.5e-4 per row) recompute that row in f64, reusing the
//    already-computed threefry bits. Output is bit-identical to the pure-f64
//    round-2 kernel, which validated with absmax 0.
//  - threefry (70 int ops x 52.4M elements) is the irreducible floor (~47us).

#define MAXDEG 128

__device__ __forceinline__ void tf_round(uint32_t& x0, uint32_t& x1, int r) {
  x0 += x1;
  x1 = (x1 << r) | (x1 >> (32 - r));  // v_alignbit_b32
  x1 ^= x0;
}

// threefry2x32, key (0, 42), counter (0, i); returns out0 ^ out1 (JAX
// partitionable 32-bit fold).
__device__ __forceinline__ uint32_t tf_bits(uint32_t i) {
  const uint32_t ks0 = 0u;
  const uint32_t ks1 = 42u;
  const uint32_t ks2 = 0x1BD11BF0u;  // 0 ^ 42 ^ 0x1BD11BDA
  uint32_t x0 = ks0;
  uint32_t x1 = i + ks1;
  tf_round(x0, x1, 13); tf_round(x0, x1, 15); tf_round(x0, x1, 26); tf_round(x0, x1, 6);
  x0 += ks1; x1 += ks2 + 1u;
  tf_round(x0, x1, 17); tf_round(x0, x1, 29); tf_round(x0, x1, 16); tf_round(x0, x1, 24);
  x0 += ks2; x1 += ks0 + 2u;
  tf_round(x0, x1, 13); tf_round(x0, x1, 15); tf_round(x0, x1, 26); tf_round(x0, x1, 6);
  x0 += ks0; x1 += ks1 + 3u;
  tf_round(x0, x1, 17); tf_round(x0, x1, 29); tf_round(x0, x1, 16); tf_round(x0, x1, 24);
  x0 += ks1; x1 += ks2 + 4u;
  tf_round(x0, x1, 13); tf_round(x0, x1, 15); tf_round(x0, x1, 26); tf_round(x0, x1, 6);
  x0 += ks2; x1 += ks0 + 5u;
  return x0 ^ x1;
}

// JAX uniform(minval=tiny, maxval=1) float from 32 random bits.
__device__ __forceinline__ float uniform_from_bits(uint32_t bits) {
  uint32_t fb = (bits >> 9) | 0x3f800000u;
  float f = __uint_as_float(fb) - 1.0f;        // [0,1), multiples of 2^-23
  return (f == 0.0f) ? 1.17549435e-38f : f;    // max(tiny, f) clamp
}

__global__ __launch_bounds__(256) void wns_kernel(
    const float* __restrict__ adj_weight,
    const int* __restrict__ adj_info,
    const int* __restrict__ ids,
    int* __restrict__ out,
    int batch, int nsamp) {
  const int lane = threadIdx.x & 63;
  const int b = blockIdx.x * 4 + (threadIdx.x >> 6);  // one wave per batch row
  if (b >= batch) return;

  const long long nid = (long long)ids[b];
  const float w0 = adj_weight[nid * MAXDEG + lane];
  const float w1 = adj_weight[nid * MAXDEG + lane + 64];
  const int n0 = adj_info[nid * MAXDEG + lane];
  const int n1 = adj_info[nid * MAXDEG + lane + 64];
  // f32 logits, computed once per b (reused across all 25 samples).
  const float lw0 = __logf(w0);
  const float lw1 = __logf(w1);

  #pragma unroll 1
  for (int s = 0; s < nsamp; ++s) {
    const uint32_t base = (uint32_t)(s * batch + b) * 128u;
    const uint32_t bits0 = tf_bits(base + (uint32_t)lane);
    const uint32_t bits1 = tf_bits(base + (uint32_t)lane + 64u);

    // f32 Gumbel scores
    const float u0 = uniform_from_bits(bits0);
    const float u1 = uniform_from_bits(bits1);
    const float z0 = lw0 - __logf(-__logf(u0));
    const float z1 = lw1 - __logf(-__logf(u1));

    float z; int d;
    if (z1 > z0) { z = z1; d = lane + 64; } else { z = z0; d = lane; }
    #pragma unroll
    for (int m = 1; m < 64; m <<= 1) {
      float oz = __shfl_xor(z, m);
      int od = __shfl_xor(d, m);
      if (oz > z || (oz == z && od < d)) { z = oz; d = od; }
    }

    // Screen: is the f32 winner unambiguous? (error bound ~6e-5 << 3e-4)
    const float thr = z - 3.0e-4f;
    const int cnt = __popcll(__ballot(z0 > thr)) + __popcll(__ballot(z1 > thr));

    if (cnt != 1) {
      // Rare exact f64 path (reuses threefry bits). Wave-uniform branch.
      const double Z0 = log((double)w0)
                      - log(-log((double)uniform_from_bits(bits0)));
      const double Z1 = log((double)w1)
                      - log(-log((double)uniform_from_bits(bits1)));
      double zz; int dd;
      if (Z1 > Z0) { zz = Z1; dd = lane + 64; } else { zz = Z0; dd = lane; }
      #pragma unroll
      for (int m = 1; m < 64; m <<= 1) {
        double oz = __shfl_xor(zz, m);
        int od = __shfl_xor(dd, m);
        if (oz > zz || (oz == zz && od < dd)) { zz = oz; dd = od; }
      }
      d = dd;
    }

    // Winner's neighbor id via cross-lane pull (no global gather).
    const int pick = (d < 64) ? n0 : n1;
    const int outv = __shfl(pick, d & 63);
    if (lane == 0) out[(long long)b * nsamp + s] = outv;
  }
}

extern "C" void kernel_launch(void* const* d_in, const int* in_sizes, int n_in,
                              void* d_out, int out_size, void* d_ws, size_t ws_size,
                              hipStream_t stream) {
  const float* adj_weight = (const float*)d_in[0];
  const int* adj_info = (const int*)d_in[1];
  const int* ids = (const int*)d_in[2];
  int batch = in_sizes[2];
  int nsamp = out_size / batch;            // 25
  int blocks = (batch + 3) / 4;            // one wave per b, 4 waves/block
  wns_kernel<<<blocks, 256, 0, stream>>>(adj_weight, adj_info, ids,
                                         (int*)d_out, batch, nsamp);
}

// Round 4
// 169.391 us; speedup vs baseline: 3.0027x; 1.0845x over previous
//
#include <hip/hip_runtime.h>
#include <stdint.h>

// WeightedNeighborSampler — exact reproduction of
// jax.random.categorical(key(42), log(w)) (partitionable threefry, XOR-fold).
//
// Round-4: structure-only change vs the validated round-3 kernel. All f32/f64
// arithmetic expressions are IDENTICAL (same __logf chain, same uniform
// construction, same 3e-4 screen, same f64 resolve) so every z value is
// bit-identical to round 3 — only the reduction/selection machinery changed:
//  - 32 lanes per (b,s) row, 4 elements/lane via float4 loads; 2 rows/wave.
//  - max-only 5-step ds_swizzle reduce (DS pipe, not VALU); argmax recovered
//    scalar-side from the screen ballots: cnt==1 => unique over-threshold bit
//    is the argmax (first occurrence trivially unique).
//  - adj_info: gather winner only (1 load/row, L2-cached across 25 samples).
//  - rare f64 fallback covers both co-rows of the wave (safe: unflagged row
//    has gap>3e-4 => f32 and f64 winners agree).

#define MAXDEG 128

__device__ __forceinline__ void tf_round(uint32_t& x0, uint32_t& x1, int r) {
  x0 += x1;
  x1 = __builtin_rotateleft32(x1, r);  // v_alignbit_b32
  x1 ^= x0;
}

// threefry2x32, key (0, 42), counter (0, i); returns out0 ^ out1 (JAX
// partitionable 32-bit fold).
__device__ __forceinline__ uint32_t tf_bits(uint32_t i) {
  const uint32_t ks0 = 0u;
  const uint32_t ks1 = 42u;
  const uint32_t ks2 = 0x1BD11BF0u;  // 0 ^ 42 ^ 0x1BD11BDA
  uint32_t x0 = ks0;
  uint32_t x1 = i + ks1;
  tf_round(x0, x1, 13); tf_round(x0, x1, 15); tf_round(x0, x1, 26); tf_round(x0, x1, 6);
  x0 += ks1; x1 += ks2 + 1u;
  tf_round(x0, x1, 17); tf_round(x0, x1, 29); tf_round(x0, x1, 16); tf_round(x0, x1, 24);
  x0 += ks2; x1 += ks0 + 2u;
  tf_round(x0, x1, 13); tf_round(x0, x1, 15); tf_round(x0, x1, 26); tf_round(x0, x1, 6);
  x0 += ks0; x1 += ks1 + 3u;
  tf_round(x0, x1, 17); tf_round(x0, x1, 29); tf_round(x0, x1, 16); tf_round(x0, x1, 24);
  x0 += ks1; x1 += ks2 + 4u;
  tf_round(x0, x1, 13); tf_round(x0, x1, 15); tf_round(x0, x1, 26); tf_round(x0, x1, 6);
  x0 += ks2; x1 += ks0 + 5u;
  return x0 ^ x1;
}

// JAX uniform(minval=tiny, maxval=1) float from 32 random bits. (== round 3)
__device__ __forceinline__ float uniform_from_bits(uint32_t bits) {
  uint32_t fb = (bits >> 9) | 0x3f800000u;
  float f = __uint_as_float(fb) - 1.0f;        // [0,1), multiples of 2^-23
  return (f == 0.0f) ? 1.17549435e-38f : f;    // max(tiny, f) clamp
}

// f32 Gumbel-perturbed logit, identical expression to round 3.
__device__ __forceinline__ float zscore(float lw, uint32_t bits) {
  return lw - __logf(-__logf(uniform_from_bits(bits)));
}

// xor-swizzle max within 32-lane halves (BitMode and=0x1F confines to halves).
#define SWZMAX(zm, pat) \
  zm = fmaxf(zm, __int_as_float(__builtin_amdgcn_ds_swizzle(__float_as_int(zm), (pat))))

__global__ __launch_bounds__(256) void wns_kernel(
    const float* __restrict__ adj_weight,
    const int* __restrict__ adj_info,
    const int* __restrict__ ids,
    int* __restrict__ out,
    int batch, int nsamp) {
  const int lane = threadIdx.x & 63;
  const int l = lane & 31;                         // lane within row
  const int wid = blockIdx.x * 4 + (threadIdx.x >> 6);
  if (2 * wid >= batch) return;                    // wave-uniform guard
  const int b = 2 * wid + (lane >> 5);             // lanes 0-31: b0, 32-63: b1

  const long long nid = (long long)ids[b];
  const float4 wv = *(const float4*)(adj_weight + nid * MAXDEG + 4 * l);
  // f32 logits, once per b (reused across all 25 samples). Same as round 3.
  const float lw0 = __logf(wv.x);
  const float lw1 = __logf(wv.y);
  const float lw2 = __logf(wv.z);
  const float lw3 = __logf(wv.w);

  uint32_t sbase = (uint32_t)b * 128u + (uint32_t)(4 * l);
  const uint32_t sstep = (uint32_t)batch * 128u;

  #pragma unroll 1
  for (int s = 0; s < nsamp; ++s, sbase += sstep) {
    const uint32_t bits0 = tf_bits(sbase + 0u);
    const uint32_t bits1 = tf_bits(sbase + 1u);
    const uint32_t bits2 = tf_bits(sbase + 2u);
    const uint32_t bits3 = tf_bits(sbase + 3u);

    const float z0 = zscore(lw0, bits0);
    const float z1 = zscore(lw1, bits1);
    const float z2 = zscore(lw2, bits2);
    const float z3 = zscore(lw3, bits3);

    // max over the row: local 4-way, then 5-step xor-swizzle across 32 lanes
    float zmax = fmaxf(fmaxf(z0, z1), fmaxf(z2, z3));
    SWZMAX(zmax, 0x041F);  // xor 1
    SWZMAX(zmax, 0x081F);  // xor 2
    SWZMAX(zmax, 0x101F);  // xor 4
    SWZMAX(zmax, 0x201F);  // xor 8
    SWZMAX(zmax, 0x401F);  // xor 16

    // Screen ballots (identical predicate to round 3)
    const float thr = zmax - 3.0e-4f;
    const unsigned long long m0 = __ballot(z0 > thr);
    const unsigned long long m1 = __ballot(z1 > thr);
    const unsigned long long m2 = __ballot(z2 > thr);
    const unsigned long long m3 = __ballot(z3 > thr);
    const uint32_t a0 = (uint32_t)m0, a1 = (uint32_t)m1,
                   a2 = (uint32_t)m2, a3 = (uint32_t)m3;
    const uint32_t c0 = (uint32_t)(m0 >> 32), c1 = (uint32_t)(m1 >> 32),
                   c2 = (uint32_t)(m2 >> 32), c3 = (uint32_t)(m3 >> 32);
    const int cntA = __popc(a0) + __popc(a1) + __popc(a2) + __popc(a3);
    const int cntB = __popc(c0) + __popc(c1) + __popc(c2) + __popc(c3);

    int d;
    if (cntA == 1 && cntB == 1) {
      // unique over-threshold element == the max == argmax (scalar extract)
      const int dA = a0 ? 4 * __builtin_ctz(a0)
                   : a1 ? 4 * __builtin_ctz(a1) + 1
                   : a2 ? 4 * __builtin_ctz(a2) + 2
                        : 4 * __builtin_ctz(a3) + 3;
      const int dB = c0 ? 4 * __builtin_ctz(c0)
                   : c1 ? 4 * __builtin_ctz(c1) + 1
                   : c2 ? 4 * __builtin_ctz(c2) + 2
                        : 4 * __builtin_ctz(c3) + 3;
      d = (lane < 32) ? dA : dB;
    } else {
      // Rare exact f64 path (reuses threefry bits), identical math to round 3.
      double bz = log((double)wv.x) - log(-log((double)uniform_from_bits(bits0)));
      int bd = 4 * l;
      const double Z1 = log((double)wv.y) - log(-log((double)uniform_from_bits(bits1)));
      if (Z1 > bz) { bz = Z1; bd = 4 * l + 1; }
      const double Z2 = log((double)wv.z) - log(-log((double)uniform_from_bits(bits2)));
      if (Z2 > bz) { bz = Z2; bd = 4 * l + 2; }
      const double Z3 = log((double)wv.w) - log(-log((double)uniform_from_bits(bits3)));
      if (Z3 > bz) { bz = Z3; bd = 4 * l + 3; }
      #pragma unroll
      for (int m = 1; m < 32; m <<= 1) {   // xor masks stay within halves
        const double oz = __shfl_xor(bz, m);
        const int od = __shfl_xor(bd, m);
        if (oz > bz || (oz == bz && od < bd)) { bz = oz; bd = od; }
      }
      d = bd;
    }

    if (l == 0) {
      out[(long long)b * nsamp + s] = adj_info[nid * MAXDEG + d];
    }
  }
}

extern "C" void kernel_launch(void* const* d_in, const int* in_sizes, int n_in,
                              void* d_out, int out_size, void* d_ws, size_t ws_size,
                              hipStream_t stream) {
  const float* adj_weight = (const float*)d_in[0];
  const int* adj_info = (const int*)d_in[1];
  const int* ids = (const int*)d_in[2];
  int batch = in_sizes[2];
  int nsamp = out_size / batch;             // 25
  int waves = (batch + 1) / 2;              // 2 rows (b) per wave
  int blocks = (waves + 3) / 4;             // 4 waves per block
  wns_kernel<<<blocks, 256, 0, stream>>>(adj_weight, adj_info, ids,
                                         (int*)d_out, batch, nsamp);
}

// Round 5
// 153.397 us; speedup vs baseline: 3.3157x; 1.1043x over previous
//
#include <hip/hip_runtime.h>
#include <stdint.h>

// WeightedNeighborSampler — exact reproduction of
// jax.random.categorical(key(42), log(w)) (partitionable threefry, XOR-fold).
//
// Round-5: instruction diet on the validated round-4 structure. Output is
// provably invariant:
//  - f32 screen chain rewritten in log2 space:
//      z = lwp - ln2*log2(-log2(u)),  lwp = __logf(w) + 0.36651292
//    (algebraically equal to round-4's z; |z32-z64| <= ~2.4e-5, screened at
//    3e-4, so the cnt==1 => argmax proof still holds with 12x margin)
//  - uniform clamp as fmaxf(f, tiny)  (identical: f in {0} U [2^-23, 1))
//  - threefry key-injection adds fused for v_add3_u32; x0==0 first round folded
//  - v_max3_f32 local max; #pragma unroll 2 on the sample loop for ILP
//  - rare f64 resolve path byte-identical to the round-2-validated chain.

#define MAXDEG 128

__device__ __forceinline__ uint32_t rotl32(uint32_t x, int r) {
  return __builtin_rotateleft32(x, r);  // v_alignbit_b32
}

// threefry2x32, key (0, 42), counter (0, i); returns out0 ^ out1 (JAX
// partitionable 32-bit fold). ks0=0, ks1=42, ks2=0x1BD11BF0.
__device__ __forceinline__ uint32_t tf_bits(uint32_t i) {
  uint32_t x0, x1;
  x1 = i + 42u;                 // ctr + ks1
  x0 = x1;                      // round 1: x0 = 0 + x1
  x1 = rotl32(x1, 13) ^ x0;
  x0 += x1; x1 = rotl32(x1, 15) ^ x0;
  x0 += x1; x1 = rotl32(x1, 26) ^ x0;
  x0 += x1; x1 = rotl32(x1,  6) ^ x0;
  // inj(ks1, ks2+1) fused with round-5 add (v_add3)
  x1 += 0x1BD11BF1u; x0 = x0 + x1 + 42u;
  x1 = rotl32(x1, 17) ^ x0;
  x0 += x1; x1 = rotl32(x1, 29) ^ x0;
  x0 += x1; x1 = rotl32(x1, 16) ^ x0;
  x0 += x1; x1 = rotl32(x1, 24) ^ x0;
  // inj(ks2, ks0+2)
  x1 += 2u; x0 = x0 + x1 + 0x1BD11BF0u;
  x1 = rotl32(x1, 13) ^ x0;
  x0 += x1; x1 = rotl32(x1, 15) ^ x0;
  x0 += x1; x1 = rotl32(x1, 26) ^ x0;
  x0 += x1; x1 = rotl32(x1,  6) ^ x0;
  // inj(ks0, ks1+3)
  x1 += 45u; x0 = x0 + x1;      // ks0 == 0
  x1 = rotl32(x1, 17) ^ x0;
  x0 += x1; x1 = rotl32(x1, 29) ^ x0;
  x0 += x1; x1 = rotl32(x1, 16) ^ x0;
  x0 += x1; x1 = rotl32(x1, 24) ^ x0;
  // inj(ks1, ks2+4)
  x1 += 0x1BD11BF4u; x0 = x0 + x1 + 42u;
  x1 = rotl32(x1, 13) ^ x0;
  x0 += x1; x1 = rotl32(x1, 15) ^ x0;
  x0 += x1; x1 = rotl32(x1, 26) ^ x0;
  x0 += x1; x1 = rotl32(x1,  6) ^ x0;
  // final inj(ks2, ks0+5) + fold
  return (x0 + 0x1BD11BF0u) ^ (x1 + 5u);
}

// JAX uniform(minval=tiny, maxval=1) float from 32 random bits.
__device__ __forceinline__ float uniform_from_bits(uint32_t bits) {
  uint32_t fb = (bits >> 9) | 0x3f800000u;
  float f = __uint_as_float(fb) - 1.0f;     // {0} U [2^-23, 1)
  return fmaxf(f, 1.17549435e-38f);         // == (f==0 ? tiny : f)
}

// f32 screen score in log2 space: lwp - ln2*log2(-log2(u)).
__device__ __forceinline__ float zscore(float lwp, uint32_t bits) {
  const float l = __log2f(uniform_from_bits(bits));   // in [-126, -1.7e-7]
  const float t = __log2f(-l);
  return __builtin_fmaf(-0.69314718056f, t, lwp);
}

// xor-swizzle max within 32-lane halves (BitMode and=0x1F confines to halves).
#define SWZMAX(zm, pat) \
  zm = fmaxf(zm, __int_as_float(__builtin_amdgcn_ds_swizzle(__float_as_int(zm), (pat))))

__global__ __launch_bounds__(256) void wns_kernel(
    const float* __restrict__ adj_weight,
    const int* __restrict__ adj_info,
    const int* __restrict__ ids,
    int* __restrict__ out,
    int batch, int nsamp) {
  const int lane = threadIdx.x & 63;
  const int l = lane & 31;                         // lane within row
  const int wid = blockIdx.x * 4 + (threadIdx.x >> 6);
  if (2 * wid >= batch) return;                    // wave-uniform guard
  const int b = 2 * wid + (lane >> 5);             // lanes 0-31: b0, 32-63: b1

  const long long nid = (long long)ids[b];
  const float4 wv = *(const float4*)(adj_weight + nid * MAXDEG + 4 * l);
  // lwp = log(w) + ln2*log2(ln2) fold-in, once per b (reused for 25 samples).
  const float lwp0 = __logf(wv.x) + 0.36651292f;
  const float lwp1 = __logf(wv.y) + 0.36651292f;
  const float lwp2 = __logf(wv.z) + 0.36651292f;
  const float lwp3 = __logf(wv.w) + 0.36651292f;

  uint32_t sbase = (uint32_t)b * 128u + (uint32_t)(4 * l);
  const uint32_t sstep = (uint32_t)batch * 128u;

  #pragma unroll 2
  for (int s = 0; s < nsamp; ++s, sbase += sstep) {
    const uint32_t bits0 = tf_bits(sbase + 0u);
    const uint32_t bits1 = tf_bits(sbase + 1u);
    const uint32_t bits2 = tf_bits(sbase + 2u);
    const uint32_t bits3 = tf_bits(sbase + 3u);

    const float z0 = zscore(lwp0, bits0);
    const float z1 = zscore(lwp1, bits1);
    const float z2 = zscore(lwp2, bits2);
    const float z3 = zscore(lwp3, bits3);

    // max over the row: local 4-way (max3+max), then 5-step xor-swizzle
    float zmax = fmaxf(fmaxf(fmaxf(z0, z1), z2), z3);  // clang folds to v_max3
    SWZMAX(zmax, 0x041F);  // xor 1
    SWZMAX(zmax, 0x081F);  // xor 2
    SWZMAX(zmax, 0x101F);  // xor 4
    SWZMAX(zmax, 0x201F);  // xor 8
    SWZMAX(zmax, 0x401F);  // xor 16

    // Screen ballots: candidates within 3e-4 of the row max
    const float thr = zmax - 3.0e-4f;
    const unsigned long long m0 = __ballot(z0 > thr);
    const unsigned long long m1 = __ballot(z1 > thr);
    const unsigned long long m2 = __ballot(z2 > thr);
    const unsigned long long m3 = __ballot(z3 > thr);
    const uint32_t a0 = (uint32_t)m0, a1 = (uint32_t)m1,
                   a2 = (uint32_t)m2, a3 = (uint32_t)m3;
    const uint32_t c0 = (uint32_t)(m0 >> 32), c1 = (uint32_t)(m1 >> 32),
                   c2 = (uint32_t)(m2 >> 32), c3 = (uint32_t)(m3 >> 32);
    const int cntA = __popc(a0) + __popc(a1) + __popc(a2) + __popc(a3);
    const int cntB = __popc(c0) + __popc(c1) + __popc(c2) + __popc(c3);

    int d;
    if (cntA == 1 && cntB == 1) {
      // unique over-threshold element == the argmax (scalar-side extract)
      const int dA = a0 ? 4 * __builtin_ctz(a0)
                   : a1 ? 4 * __builtin_ctz(a1) + 1
                   : a2 ? 4 * __builtin_ctz(a2) + 2
                        : 4 * __builtin_ctz(a3) + 3;
      const int dB = c0 ? 4 * __builtin_ctz(c0)
                   : c1 ? 4 * __builtin_ctz(c1) + 1
                   : c2 ? 4 * __builtin_ctz(c2) + 2
                        : 4 * __builtin_ctz(c3) + 3;
      d = (lane < 32) ? dA : dB;
    } else {
      // Rare exact f64 path (reuses threefry bits) — byte-identical math to
      // the round-2-validated chain.
      double bz = log((double)wv.x) - log(-log((double)uniform_from_bits(bits0)));
      int bd = 4 * l;
      const double Z1 = log((double)wv.y) - log(-log((double)uniform_from_bits(bits1)));
      if (Z1 > bz) { bz = Z1; bd = 4 * l + 1; }
      const double Z2 = log((double)wv.z) - log(-log((double)uniform_from_bits(bits2)));
      if (Z2 > bz) { bz = Z2; bd = 4 * l + 2; }
      const double Z3 = log((double)wv.w) - log(-log((double)uniform_from_bits(bits3)));
      if (Z3 > bz) { bz = Z3; bd = 4 * l + 3; }
      #pragma unroll
      for (int m = 1; m < 32; m <<= 1) {   // xor masks stay within halves
        const double oz = __shfl_xor(bz, m);
        const int od = __shfl_xor(bd, m);
        if (oz > bz || (oz == bz && od < bd)) { bz = oz; bd = od; }
      }
      d = bd;
    }

    if (l == 0) {
      out[(long long)b * nsamp + s] = adj_info[nid * MAXDEG + d];
    }
  }
}

extern "C" void kernel_launch(void* const* d_in, const int* in_sizes, int n_in,
                              void* d_out, int out_size, void* d_ws, size_t ws_size,
                              hipStream_t stream) {
  const float* adj_weight = (const float*)d_in[0];
  const int* adj_info = (const int*)d_in[1];
  const int* ids = (const int*)d_in[2];
  int batch = in_sizes[2];
  int nsamp = out_size / batch;             // 25
  int waves = (batch + 1) / 2;              // 2 rows (b) per wave
  int blocks = (waves + 3) / 4;             // 4 waves per block
  wns_kernel<<<blocks, 256, 0, stream>>>(adj_weight, adj_info, ids,
                                         (int*)d_out, batch, nsamp);
}

// Round 6
// 148.488 us; speedup vs baseline: 3.4253x; 1.0331x over previous
//
#include <hip/hip_runtime.h>
#include <stdint.h>

// WeightedNeighborSampler — exact reproduction of
// jax.random.categorical(key(42), log(w)) (partitionable threefry, XOR-fold).
//
// Round-6: latency attack on the validated round-5 numerics (z values are
// bit-identical; fmax is exactly associative/commutative so the reduction
// reorder cannot change zmax; screen threshold and f64 resolve unchanged):
//  - branchless hot loop: the rare cnt!=1 cases are RECORDED in two per-wave
//    scalar bitmasks and resolved in a cold noinline f64 loop after the
//    25-sample loop (expected ~120 executions grid-wide). No per-iteration
//    control flow -> scheduler can pipeline across samples.
//  - reduce: 4x v_max+DPP row_ror{1,2,4,8} (VALU pipe, low latency) + one
//    ds_swizzle xor-16 for the cross-16 exchange, replacing 5 serial LDS hops.
//  - #pragma unroll 5, __launch_bounds__(256,8) pins 8 waves/SIMD (VGPR<=64).

#define MAXDEG 128

__device__ __forceinline__ uint32_t rotl32(uint32_t x, int r) {
  return __builtin_rotateleft32(x, r);  // v_alignbit_b32
}

// threefry2x32, key (0, 42), counter (0, i); returns out0 ^ out1 (JAX
// partitionable 32-bit fold). ks0=0, ks1=42, ks2=0x1BD11BF0. (== round 5)
__device__ __forceinline__ uint32_t tf_bits(uint32_t i) {
  uint32_t x0, x1;
  x1 = i + 42u;                 // ctr + ks1
  x0 = x1;                      // round 1: x0 = 0 + x1
  x1 = rotl32(x1, 13) ^ x0;
  x0 += x1; x1 = rotl32(x1, 15) ^ x0;
  x0 += x1; x1 = rotl32(x1, 26) ^ x0;
  x0 += x1; x1 = rotl32(x1,  6) ^ x0;
  x1 += 0x1BD11BF1u; x0 = x0 + x1 + 42u;      // inj(ks1, ks2+1)
  x1 = rotl32(x1, 17) ^ x0;
  x0 += x1; x1 = rotl32(x1, 29) ^ x0;
  x0 += x1; x1 = rotl32(x1, 16) ^ x0;
  x0 += x1; x1 = rotl32(x1, 24) ^ x0;
  x1 += 2u; x0 = x0 + x1 + 0x1BD11BF0u;       // inj(ks2, ks0+2)
  x1 = rotl32(x1, 13) ^ x0;
  x0 += x1; x1 = rotl32(x1, 15) ^ x0;
  x0 += x1; x1 = rotl32(x1, 26) ^ x0;
  x0 += x1; x1 = rotl32(x1,  6) ^ x0;
  x1 += 45u; x0 = x0 + x1;                    // inj(ks0, ks1+3), ks0==0
  x1 = rotl32(x1, 17) ^ x0;
  x0 += x1; x1 = rotl32(x1, 29) ^ x0;
  x0 += x1; x1 = rotl32(x1, 16) ^ x0;
  x0 += x1; x1 = rotl32(x1, 24) ^ x0;
  x1 += 0x1BD11BF4u; x0 = x0 + x1 + 42u;      // inj(ks1, ks2+4)
  x1 = rotl32(x1, 13) ^ x0;
  x0 += x1; x1 = rotl32(x1, 15) ^ x0;
  x0 += x1; x1 = rotl32(x1, 26) ^ x0;
  x0 += x1; x1 = rotl32(x1,  6) ^ x0;
  return (x0 + 0x1BD11BF0u) ^ (x1 + 5u);      // final inj(ks2, ks0+5) + fold
}

// JAX uniform(minval=tiny, maxval=1) float from 32 random bits.
__device__ __forceinline__ float uniform_from_bits(uint32_t bits) {
  uint32_t fb = (bits >> 9) | 0x3f800000u;
  float f = __uint_as_float(fb) - 1.0f;     // {0} U [2^-23, 1)
  return fmaxf(f, 1.17549435e-38f);         // == (f==0 ? tiny : f)
}

// f32 screen score in log2 space: lwp - ln2*log2(-log2(u)). (== round 5)
__device__ __forceinline__ float zscore(float lwp, uint32_t bits) {
  const float l = __log2f(uniform_from_bits(bits));
  const float t = __log2f(-l);
  return __builtin_fmaf(-0.69314718056f, t, lwp);
}

// v_max with DPP row_ror:K (all-reduce within each 16-lane row).
template <int CTRL>
__device__ __forceinline__ float dpp_max_step(float z) {
  const int t = __builtin_amdgcn_update_dpp(0, __float_as_int(z), CTRL, 0xF, 0xF, true);
  return fmaxf(z, __int_as_float(t));
}

// xor-swizzle max (BitMode and=0x1F confines to 32-lane halves).
__device__ __forceinline__ float swz_max16(float z) {
  return fmaxf(z, __int_as_float(
      __builtin_amdgcn_ds_swizzle(__float_as_int(z), 0x401F)));  // xor 16
}

// Cold exact-f64 resolve for one flagged (row, sample). Byte-identical math
// to the round-2-validated chain. storeLane = 0 (row A) or 32 (row B).
__device__ __attribute__((noinline)) void resolve_f64(
    float4 wv, uint32_t sbase, int l, int lane, int storeLane,
    const int* __restrict__ adj_info, long long nid,
    int* __restrict__ out, long long outIdx) {
  const uint32_t bits0 = tf_bits(sbase + 0u);
  const uint32_t bits1 = tf_bits(sbase + 1u);
  const uint32_t bits2 = tf_bits(sbase + 2u);
  const uint32_t bits3 = tf_bits(sbase + 3u);
  double bz = log((double)wv.x) - log(-log((double)uniform_from_bits(bits0)));
  int bd = 4 * l;
  const double Z1 = log((double)wv.y) - log(-log((double)uniform_from_bits(bits1)));
  if (Z1 > bz) { bz = Z1; bd = 4 * l + 1; }
  const double Z2 = log((double)wv.z) - log(-log((double)uniform_from_bits(bits2)));
  if (Z2 > bz) { bz = Z2; bd = 4 * l + 2; }
  const double Z3 = log((double)wv.w) - log(-log((double)uniform_from_bits(bits3)));
  if (Z3 > bz) { bz = Z3; bd = 4 * l + 3; }
  #pragma unroll
  for (int m = 1; m < 32; m <<= 1) {   // xor masks stay within 32-halves
    const double oz = __shfl_xor(bz, m);
    const int od = __shfl_xor(bd, m);
    if (oz > bz || (oz == bz && od < bd)) { bz = oz; bd = od; }
  }
  if (lane == storeLane) out[outIdx] = adj_info[nid * MAXDEG + bd];
}

__global__ __launch_bounds__(256, 8) void wns_kernel(
    const float* __restrict__ adj_weight,
    const int* __restrict__ adj_info,
    const int* __restrict__ ids,
    int* __restrict__ out,
    int batch, int nsamp) {
  const int lane = threadIdx.x & 63;
  const int l = lane & 31;                         // lane within row
  const int wid = blockIdx.x * 4 + (threadIdx.x >> 6);
  if (2 * wid >= batch) return;                    // wave-uniform guard
  const int b = 2 * wid + (lane >> 5);             // lanes 0-31: b0, 32-63: b1

  const long long nid = (long long)ids[b];
  const float4 wv = *(const float4*)(adj_weight + nid * MAXDEG + 4 * l);
  // lwp = log(w) + ln2*log2(ln2), once per b (reused for 25 samples).
  const float lwp0 = __logf(wv.x) + 0.36651292f;
  const float lwp1 = __logf(wv.y) + 0.36651292f;
  const float lwp2 = __logf(wv.z) + 0.36651292f;
  const float lwp3 = __logf(wv.w) + 0.36651292f;

  uint32_t sbase = (uint32_t)b * 128u + (uint32_t)(4 * l);
  const uint32_t sstep = (uint32_t)batch * 128u;

  uint32_t flagA = 0u, flagB = 0u;   // wave-uniform -> SGPR

  #pragma unroll 5
  for (int s = 0; s < nsamp; ++s, sbase += sstep) {
    const uint32_t bits0 = tf_bits(sbase + 0u);
    const uint32_t bits1 = tf_bits(sbase + 1u);
    const uint32_t bits2 = tf_bits(sbase + 2u);
    const uint32_t bits3 = tf_bits(sbase + 3u);

    const float z0 = zscore(lwp0, bits0);
    const float z1 = zscore(lwp1, bits1);
    const float z2 = zscore(lwp2, bits2);
    const float z3 = zscore(lwp3, bits3);

    // row max: local 4-way, DPP ror{1,2,4,8} within 16, one xor-16 swizzle
    float zmax = fmaxf(fmaxf(fmaxf(z0, z1), z2), z3);
    zmax = dpp_max_step<0x121>(zmax);  // row_ror:1
    zmax = dpp_max_step<0x122>(zmax);  // row_ror:2
    zmax = dpp_max_step<0x124>(zmax);  // row_ror:4
    zmax = dpp_max_step<0x128>(zmax);  // row_ror:8
    zmax = swz_max16(zmax);            // xor 16 (within 32-half)

    // Screen ballots: candidates within 3e-4 of the row max
    const float thr = zmax - 3.0e-4f;
    const unsigned long long m0 = __ballot(z0 > thr);
    const unsigned long long m1 = __ballot(z1 > thr);
    const unsigned long long m2 = __ballot(z2 > thr);
    const unsigned long long m3 = __ballot(z3 > thr);
    const uint32_t a0 = (uint32_t)m0, a1 = (uint32_t)m1,
                   a2 = (uint32_t)m2, a3 = (uint32_t)m3;
    const uint32_t c0 = (uint32_t)(m0 >> 32), c1 = (uint32_t)(m1 >> 32),
                   c2 = (uint32_t)(m2 >> 32), c3 = (uint32_t)(m3 >> 32);
    const int cntA = __popc(a0) + __popc(a1) + __popc(a2) + __popc(a3);
    const int cntB = __popc(c0) + __popc(c1) + __popc(c2) + __popc(c3);

    // fast-path argmax (valid when cnt==1; flagged rows overwritten later)
    const int dA = a0 ? 4 * __builtin_ctz(a0)
                 : a1 ? 4 * __builtin_ctz(a1) + 1
                 : a2 ? 4 * __builtin_ctz(a2) + 2
                 : a3 ? 4 * __builtin_ctz(a3) + 3 : 0;
    const int dB = c0 ? 4 * __builtin_ctz(c0)
                 : c1 ? 4 * __builtin_ctz(c1) + 1
                 : c2 ? 4 * __builtin_ctz(c2) + 2
                 : c3 ? 4 * __builtin_ctz(c3) + 3 : 0;
    const int d = (lane < 32) ? dA : dB;
    if (l == 0) out[(long long)b * nsamp + s] = adj_info[nid * MAXDEG + d];

    flagA |= (cntA != 1) ? (1u << s) : 0u;   // SALU bookkeeping
    flagB |= (cntB != 1) ? (1u << s) : 0u;
  }

  // Cold exact resolve of flagged (row, sample) pairs (expected ~0 per wave).
  const uint32_t rowbase = (uint32_t)b * 128u + (uint32_t)(4 * l);
  for (uint32_t m = flagA; m; m &= m - 1u) {
    const int s = __builtin_ctz(m);
    resolve_f64(wv, rowbase + (uint32_t)s * sstep, l, lane, 0,
                adj_info, nid, out, (long long)b * nsamp + s);
  }
  for (uint32_t m = flagB; m; m &= m - 1u) {
    const int s = __builtin_ctz(m);
    resolve_f64(wv, rowbase + (uint32_t)s * sstep, l, lane, 32,
                adj_info, nid, out, (long long)b * nsamp + s);
  }
}

extern "C" void kernel_launch(void* const* d_in, const int* in_sizes, int n_in,
                              void* d_out, int out_size, void* d_ws, size_t ws_size,
                              hipStream_t stream) {
  const float* adj_weight = (const float*)d_in[0];
  const int* adj_info = (const int*)d_in[1];
  const int* ids = (const int*)d_in[2];
  int batch = in_sizes[2];
  int nsamp = out_size / batch;             // 25
  int waves = (batch + 1) / 2;              // 2 rows (b) per wave
  int blocks = (waves + 3) / 4;             // 4 waves per block
  wns_kernel<<<blocks, 256, 0, stream>>>(adj_weight, adj_info, ids,
                                         (int*)d_out, batch, nsamp);
}

// Round 8
// 146.217 us; speedup vs baseline: 3.4785x; 1.0155x over previous
//
#include <hip/hip_runtime.h>
#include <stdint.h>

// WeightedNeighborSampler — exact reproduction of
// jax.random.categorical(key(42), log(w)) (partitionable threefry, XOR-fold).
//
// Round-8 = round-7 with the unsupported __builtin_amdgcn_writelane replaced
// by predicated selects (v_cmp_eq + v_cndmask). Hot loop is memory-free and
// side-effect-free; numerics bit-identical to the validated R5/R6 lineage:
//  - per-iteration winner index d (uniform per 32-half) deposited into a
//    per-lane accumulator: lane s <- row-A d(s), lane 32+s <- row-B d(s).
//  - epilogue: one coalesced adj_info gather + one contiguous 25-int store
//    per row (lanes l<25 of each half).
//  - rare cnt!=1 rows: cold noinline f64 resolve (byte-identical chain),
//    patched via __shfl broadcast + predicated select before the store.

#define MAXDEG 128

__device__ __forceinline__ uint32_t rotl32(uint32_t x, int r) {
  return __builtin_rotateleft32(x, r);  // v_alignbit_b32
}

// threefry2x32, key (0, 42), counter (0, i); returns out0 ^ out1 (JAX
// partitionable 32-bit fold). ks0=0, ks1=42, ks2=0x1BD11BF0.
__device__ __forceinline__ uint32_t tf_bits(uint32_t i) {
  uint32_t x0, x1;
  x1 = i + 42u;                 // ctr + ks1
  x0 = x1;                      // round 1: x0 = 0 + x1
  x1 = rotl32(x1, 13) ^ x0;
  x0 += x1; x1 = rotl32(x1, 15) ^ x0;
  x0 += x1; x1 = rotl32(x1, 26) ^ x0;
  x0 += x1; x1 = rotl32(x1,  6) ^ x0;
  x1 += 0x1BD11BF1u; x0 = x0 + x1 + 42u;      // inj(ks1, ks2+1)
  x1 = rotl32(x1, 17) ^ x0;
  x0 += x1; x1 = rotl32(x1, 29) ^ x0;
  x0 += x1; x1 = rotl32(x1, 16) ^ x0;
  x0 += x1; x1 = rotl32(x1, 24) ^ x0;
  x1 += 2u; x0 = x0 + x1 + 0x1BD11BF0u;       // inj(ks2, ks0+2)
  x1 = rotl32(x1, 13) ^ x0;
  x0 += x1; x1 = rotl32(x1, 15) ^ x0;
  x0 += x1; x1 = rotl32(x1, 26) ^ x0;
  x0 += x1; x1 = rotl32(x1,  6) ^ x0;
  x1 += 45u; x0 = x0 + x1;                    // inj(ks0, ks1+3), ks0==0
  x1 = rotl32(x1, 17) ^ x0;
  x0 += x1; x1 = rotl32(x1, 29) ^ x0;
  x0 += x1; x1 = rotl32(x1, 16) ^ x0;
  x0 += x1; x1 = rotl32(x1, 24) ^ x0;
  x1 += 0x1BD11BF4u; x0 = x0 + x1 + 42u;      // inj(ks1, ks2+4)
  x1 = rotl32(x1, 13) ^ x0;
  x0 += x1; x1 = rotl32(x1, 15) ^ x0;
  x0 += x1; x1 = rotl32(x1, 26) ^ x0;
  x0 += x1; x1 = rotl32(x1,  6) ^ x0;
  return (x0 + 0x1BD11BF0u) ^ (x1 + 5u);      // final inj(ks2, ks0+5) + fold
}

// JAX uniform(minval=tiny, maxval=1) float from 32 random bits.
__device__ __forceinline__ float uniform_from_bits(uint32_t bits) {
  uint32_t fb = (bits >> 9) | 0x3f800000u;
  float f = __uint_as_float(fb) - 1.0f;     // {0} U [2^-23, 1)
  return fmaxf(f, 1.17549435e-38f);         // == (f==0 ? tiny : f)
}

// f32 screen score in log2 space: lwp - ln2*log2(-log2(u)).
__device__ __forceinline__ float zscore(float lwp, uint32_t bits) {
  const float l = __log2f(uniform_from_bits(bits));
  const float t = __log2f(-l);
  return __builtin_fmaf(-0.69314718056f, t, lwp);
}

// v_max with DPP row_ror:K (all-reduce within each 16-lane row).
template <int CTRL>
__device__ __forceinline__ float dpp_max_step(float z) {
  const int t = __builtin_amdgcn_update_dpp(0, __float_as_int(z), CTRL, 0xF, 0xF, true);
  return fmaxf(z, __int_as_float(t));
}

// xor-swizzle max (BitMode and=0x1F confines to 32-lane halves).
__device__ __forceinline__ float swz_max16(float z) {
  return fmaxf(z, __int_as_float(
      __builtin_amdgcn_ds_swizzle(__float_as_int(z), 0x401F)));  // xor 16
}

// Cold exact-f64 argmax for one sample (both halves at once). Byte-identical
// math to the round-2-validated chain. Returns bd (uniform within each half).
__device__ __attribute__((noinline)) int resolve_f64(
    float4 wv, uint32_t sbase, int l) {
  const uint32_t bits0 = tf_bits(sbase + 0u);
  const uint32_t bits1 = tf_bits(sbase + 1u);
  const uint32_t bits2 = tf_bits(sbase + 2u);
  const uint32_t bits3 = tf_bits(sbase + 3u);
  double bz = log((double)wv.x) - log(-log((double)uniform_from_bits(bits0)));
  int bd = 4 * l;
  const double Z1 = log((double)wv.y) - log(-log((double)uniform_from_bits(bits1)));
  if (Z1 > bz) { bz = Z1; bd = 4 * l + 1; }
  const double Z2 = log((double)wv.z) - log(-log((double)uniform_from_bits(bits2)));
  if (Z2 > bz) { bz = Z2; bd = 4 * l + 2; }
  const double Z3 = log((double)wv.w) - log(-log((double)uniform_from_bits(bits3)));
  if (Z3 > bz) { bz = Z3; bd = 4 * l + 3; }
  #pragma unroll
  for (int m = 1; m < 32; m <<= 1) {   // xor masks stay within 32-halves
    const double oz = __shfl_xor(bz, m);
    const int od = __shfl_xor(bd, m);
    if (oz > bz || (oz == bz && od < bd)) { bz = oz; bd = od; }
  }
  return bd;
}

__global__ __launch_bounds__(256, 8) void wns_kernel(
    const float* __restrict__ adj_weight,
    const int* __restrict__ adj_info,
    const int* __restrict__ ids,
    int* __restrict__ out,
    int batch, int nsamp) {
  const int lane = threadIdx.x & 63;
  const int l = lane & 31;                         // lane within row
  const int wid = blockIdx.x * 4 + (threadIdx.x >> 6);
  if (2 * wid >= batch) return;                    // wave-uniform guard
  const int b = 2 * wid + (lane >> 5);             // lanes 0-31: b0, 32-63: b1

  const int nid = ids[b];                          // < 1e5, 32-bit math ok
  const float4 wv = *(const float4*)(adj_weight + nid * MAXDEG + 4 * l);
  // lwp = log(w) + ln2*log2(ln2), once per b (reused for 25 samples).
  const float lwp0 = __logf(wv.x) + 0.36651292f;
  const float lwp1 = __logf(wv.y) + 0.36651292f;
  const float lwp2 = __logf(wv.z) + 0.36651292f;
  const float lwp3 = __logf(wv.w) + 0.36651292f;

  uint32_t sbase = (uint32_t)b * 128u + (uint32_t)(4 * l);
  const uint32_t sstep = (uint32_t)batch * 128u;

  uint32_t flagA = 0u, flagB = 0u;   // wave-uniform -> SGPR
  int dAcc = 0;                      // lane s: row-A d(s); lane 32+s: row-B d(s)

  #pragma unroll 5
  for (int s = 0; s < nsamp; ++s, sbase += sstep) {
    const uint32_t bits0 = tf_bits(sbase + 0u);
    const uint32_t bits1 = tf_bits(sbase + 1u);
    const uint32_t bits2 = tf_bits(sbase + 2u);
    const uint32_t bits3 = tf_bits(sbase + 3u);

    const float z0 = zscore(lwp0, bits0);
    const float z1 = zscore(lwp1, bits1);
    const float z2 = zscore(lwp2, bits2);
    const float z3 = zscore(lwp3, bits3);

    // row max: local 4-way, DPP ror{1,2,4,8} within 16, one xor-16 swizzle
    float zmax = fmaxf(fmaxf(fmaxf(z0, z1), z2), z3);
    zmax = dpp_max_step<0x121>(zmax);  // row_ror:1
    zmax = dpp_max_step<0x122>(zmax);  // row_ror:2
    zmax = dpp_max_step<0x124>(zmax);  // row_ror:4
    zmax = dpp_max_step<0x128>(zmax);  // row_ror:8
    zmax = swz_max16(zmax);            // xor 16 (within 32-half)

    // Screen ballots: candidates within 3e-4 of the row max
    const float thr = zmax - 3.0e-4f;
    const unsigned long long m0 = __ballot(z0 > thr);
    const unsigned long long m1 = __ballot(z1 > thr);
    const unsigned long long m2 = __ballot(z2 > thr);
    const unsigned long long m3 = __ballot(z3 > thr);
    const uint32_t a0 = (uint32_t)m0, a1 = (uint32_t)m1,
                   a2 = (uint32_t)m2, a3 = (uint32_t)m3;
    const uint32_t c0 = (uint32_t)(m0 >> 32), c1 = (uint32_t)(m1 >> 32),
                   c2 = (uint32_t)(m2 >> 32), c3 = (uint32_t)(m3 >> 32);
    const int cntA = __popc(a0) + __popc(a1) + __popc(a2) + __popc(a3);
    const int cntB = __popc(c0) + __popc(c1) + __popc(c2) + __popc(c3);

    // fast-path argmax (uniform per half; valid when cnt==1, patched later)
    const int dA = a0 ? 4 * __builtin_ctz(a0)
                 : a1 ? 4 * __builtin_ctz(a1) + 1
                 : a2 ? 4 * __builtin_ctz(a2) + 2
                 : a3 ? 4 * __builtin_ctz(a3) + 3 : 0;
    const int dB = c0 ? 4 * __builtin_ctz(c0)
                 : c1 ? 4 * __builtin_ctz(c1) + 1
                 : c2 ? 4 * __builtin_ctz(c2) + 2
                 : c3 ? 4 * __builtin_ctz(c3) + 3 : 0;
    // deposit: lane s <- dA, lane 32+s <- dB (v_cmp_eq + v_cndmask each)
    dAcc = (lane == s) ? dA : dAcc;
    dAcc = (lane == s + 32) ? dB : dAcc;

    flagA |= (cntA != 1) ? (1u << s) : 0u;   // SALU bookkeeping
    flagB |= (cntB != 1) ? (1u << s) : 0u;
  }

  // Cold exact resolve of flagged samples (expected ~0 per wave).
  const uint32_t rowbase = (uint32_t)b * 128u + (uint32_t)(4 * l);
  for (uint32_t m = flagA | flagB; m; m &= m - 1u) {
    const int s = __builtin_ctz(m);
    const int bd = resolve_f64(wv, rowbase + (uint32_t)s * sstep, l);
    const int bdA = __shfl(bd, 0);     // row-A winner (broadcast)
    const int bdB = __shfl(bd, 32);    // row-B winner (broadcast)
    if (((flagA >> s) & 1u) && lane == s) dAcc = bdA;
    if (((flagB >> s) & 1u) && lane == s + 32) dAcc = bdB;
  }

  // Epilogue: one coalesced gather + one contiguous store per row.
  if (l < nsamp) {
    out[b * nsamp + l] = adj_info[nid * MAXDEG + dAcc];
  }
}

extern "C" void kernel_launch(void* const* d_in, const int* in_sizes, int n_in,
                              void* d_out, int out_size, void* d_ws, size_t ws_size,
                              hipStream_t stream) {
  const float* adj_weight = (const float*)d_in[0];
  const int* adj_info = (const int*)d_in[1];
  const int* ids = (const int*)d_in[2];
  int batch = in_sizes[2];
  int nsamp = out_size / batch;             // 25 (<=32 required by flag masks)
  int waves = (batch + 1) / 2;              // 2 rows (b) per wave
  int blocks = (waves + 3) / 4;             // 4 waves per block
  wns_kernel<<<blocks, 256, 0, stream>>>(adj_weight, adj_info, ids,
                                         (int*)d_out, batch, nsamp);
}

// Round 9
// 145.098 us; speedup vs baseline: 3.5054x; 1.0077x over previous
//
#include <hip/hip_runtime.h>
#include <stdint.h>

// WeightedNeighborSampler — exact reproduction of
// jax.random.categorical(key(42), log(w)) (partitionable threefry, XOR-fold).
//
// Round-9: hand-pipelined 2-sample interleave (compiler ignored #pragma
// unroll — VGPR stayed 24). Each double-iteration computes all 8 threefry
// chains (samples s, s+1) in one straight-line block, then runs the two
// reduce/screen/deposit tails. Doubles cipher-phase ILP; numerics and the
// screen->f64-resolve contract are bit-identical to the validated lineage.

#define MAXDEG 128

__device__ __forceinline__ uint32_t rotl32(uint32_t x, int r) {
  return __builtin_rotateleft32(x, r);  // v_alignbit_b32
}

// threefry2x32, key (0, 42), counter (0, i); returns out0 ^ out1 (JAX
// partitionable 32-bit fold). ks0=0, ks1=42, ks2=0x1BD11BF0.
__device__ __forceinline__ uint32_t tf_bits(uint32_t i) {
  uint32_t x0, x1;
  x1 = i + 42u;                 // ctr + ks1
  x0 = x1;                      // round 1: x0 = 0 + x1
  x1 = rotl32(x1, 13) ^ x0;
  x0 += x1; x1 = rotl32(x1, 15) ^ x0;
  x0 += x1; x1 = rotl32(x1, 26) ^ x0;
  x0 += x1; x1 = rotl32(x1,  6) ^ x0;
  x1 += 0x1BD11BF1u; x0 = x0 + x1 + 42u;      // inj(ks1, ks2+1)
  x1 = rotl32(x1, 17) ^ x0;
  x0 += x1; x1 = rotl32(x1, 29) ^ x0;
  x0 += x1; x1 = rotl32(x1, 16) ^ x0;
  x0 += x1; x1 = rotl32(x1, 24) ^ x0;
  x1 += 2u; x0 = x0 + x1 + 0x1BD11BF0u;       // inj(ks2, ks0+2)
  x1 = rotl32(x1, 13) ^ x0;
  x0 += x1; x1 = rotl32(x1, 15) ^ x0;
  x0 += x1; x1 = rotl32(x1, 26) ^ x0;
  x0 += x1; x1 = rotl32(x1,  6) ^ x0;
  x1 += 45u; x0 = x0 + x1;                    // inj(ks0, ks1+3), ks0==0
  x1 = rotl32(x1, 17) ^ x0;
  x0 += x1; x1 = rotl32(x1, 29) ^ x0;
  x0 += x1; x1 = rotl32(x1, 16) ^ x0;
  x0 += x1; x1 = rotl32(x1, 24) ^ x0;
  x1 += 0x1BD11BF4u; x0 = x0 + x1 + 42u;      // inj(ks1, ks2+4)
  x1 = rotl32(x1, 13) ^ x0;
  x0 += x1; x1 = rotl32(x1, 15) ^ x0;
  x0 += x1; x1 = rotl32(x1, 26) ^ x0;
  x0 += x1; x1 = rotl32(x1,  6) ^ x0;
  return (x0 + 0x1BD11BF0u) ^ (x1 + 5u);      // final inj(ks2, ks0+5) + fold
}

// JAX uniform(minval=tiny, maxval=1) float from 32 random bits.
__device__ __forceinline__ float uniform_from_bits(uint32_t bits) {
  uint32_t fb = (bits >> 9) | 0x3f800000u;
  float f = __uint_as_float(fb) - 1.0f;     // {0} U [2^-23, 1)
  return fmaxf(f, 1.17549435e-38f);         // == (f==0 ? tiny : f)
}

// f32 screen score in log2 space: lwp - ln2*log2(-log2(u)).
__device__ __forceinline__ float zscore(float lwp, uint32_t bits) {
  const float l = __log2f(uniform_from_bits(bits));
  const float t = __log2f(-l);
  return __builtin_fmaf(-0.69314718056f, t, lwp);
}

// v_max with DPP row_ror:K (all-reduce within each 16-lane row).
template <int CTRL>
__device__ __forceinline__ float dpp_max_step(float z) {
  const int t = __builtin_amdgcn_update_dpp(0, __float_as_int(z), CTRL, 0xF, 0xF, true);
  return fmaxf(z, __int_as_float(t));
}

// xor-swizzle max (BitMode and=0x1F confines to 32-lane halves).
__device__ __forceinline__ float swz_max16(float z) {
  return fmaxf(z, __int_as_float(
      __builtin_amdgcn_ds_swizzle(__float_as_int(z), 0x401F)));  // xor 16
}

// Cold exact-f64 argmax for one sample (both halves at once). Byte-identical
// math to the round-2-validated chain. Returns bd (uniform within each half).
__device__ __attribute__((noinline)) int resolve_f64(
    float4 wv, uint32_t sbase, int l) {
  const uint32_t bits0 = tf_bits(sbase + 0u);
  const uint32_t bits1 = tf_bits(sbase + 1u);
  const uint32_t bits2 = tf_bits(sbase + 2u);
  const uint32_t bits3 = tf_bits(sbase + 3u);
  double bz = log((double)wv.x) - log(-log((double)uniform_from_bits(bits0)));
  int bd = 4 * l;
  const double Z1 = log((double)wv.y) - log(-log((double)uniform_from_bits(bits1)));
  if (Z1 > bz) { bz = Z1; bd = 4 * l + 1; }
  const double Z2 = log((double)wv.z) - log(-log((double)uniform_from_bits(bits2)));
  if (Z2 > bz) { bz = Z2; bd = 4 * l + 2; }
  const double Z3 = log((double)wv.w) - log(-log((double)uniform_from_bits(bits3)));
  if (Z3 > bz) { bz = Z3; bd = 4 * l + 3; }
  #pragma unroll
  for (int m = 1; m < 32; m <<= 1) {   // xor masks stay within 32-halves
    const double oz = __shfl_xor(bz, m);
    const int od = __shfl_xor(bd, m);
    if (oz > bz || (oz == bz && od < bd)) { bz = oz; bd = od; }
  }
  return bd;
}

struct TailState {
  uint32_t flagA, flagB;
  int dAcc;
};

// One sample's reduce/screen/deposit tail from its 4 precomputed bit words.
__device__ __forceinline__ void sample_tail(
    int s, int lane,
    float lwp0, float lwp1, float lwp2, float lwp3,
    uint32_t bits0, uint32_t bits1, uint32_t bits2, uint32_t bits3,
    TailState& st) {
  const float z0 = zscore(lwp0, bits0);
  const float z1 = zscore(lwp1, bits1);
  const float z2 = zscore(lwp2, bits2);
  const float z3 = zscore(lwp3, bits3);

  // row max: local 4-way, DPP ror{1,2,4,8} within 16, one xor-16 swizzle
  float zmax = fmaxf(fmaxf(fmaxf(z0, z1), z2), z3);
  zmax = dpp_max_step<0x121>(zmax);  // row_ror:1
  zmax = dpp_max_step<0x122>(zmax);  // row_ror:2
  zmax = dpp_max_step<0x124>(zmax);  // row_ror:4
  zmax = dpp_max_step<0x128>(zmax);  // row_ror:8
  zmax = swz_max16(zmax);            // xor 16 (within 32-half)

  // Screen ballots: candidates within 3e-4 of the row max
  const float thr = zmax - 3.0e-4f;
  const unsigned long long m0 = __ballot(z0 > thr);
  const unsigned long long m1 = __ballot(z1 > thr);
  const unsigned long long m2 = __ballot(z2 > thr);
  const unsigned long long m3 = __ballot(z3 > thr);
  const uint32_t a0 = (uint32_t)m0, a1 = (uint32_t)m1,
                 a2 = (uint32_t)m2, a3 = (uint32_t)m3;
  const uint32_t c0 = (uint32_t)(m0 >> 32), c1 = (uint32_t)(m1 >> 32),
                 c2 = (uint32_t)(m2 >> 32), c3 = (uint32_t)(m3 >> 32);
  const int cntA = __popc(a0) + __popc(a1) + __popc(a2) + __popc(a3);
  const int cntB = __popc(c0) + __popc(c1) + __popc(c2) + __popc(c3);

  // fast-path argmax (uniform per half; valid when cnt==1, patched later)
  const int dA = a0 ? 4 * __builtin_ctz(a0)
               : a1 ? 4 * __builtin_ctz(a1) + 1
               : a2 ? 4 * __builtin_ctz(a2) + 2
               : a3 ? 4 * __builtin_ctz(a3) + 3 : 0;
  const int dB = c0 ? 4 * __builtin_ctz(c0)
               : c1 ? 4 * __builtin_ctz(c1) + 1
               : c2 ? 4 * __builtin_ctz(c2) + 2
               : c3 ? 4 * __builtin_ctz(c3) + 3 : 0;
  // deposit: lane s <- dA, lane 32+s <- dB
  const int dSel = (lane < 32) ? dA : dB;
  st.dAcc = ((lane & 31) == s) ? dSel : st.dAcc;

  st.flagA |= (cntA != 1) ? (1u << s) : 0u;   // SALU bookkeeping
  st.flagB |= (cntB != 1) ? (1u << s) : 0u;
}

__global__ __launch_bounds__(256, 8) void wns_kernel(
    const float* __restrict__ adj_weight,
    const int* __restrict__ adj_info,
    const int* __restrict__ ids,
    int* __restrict__ out,
    int batch, int nsamp) {
  const int lane = threadIdx.x & 63;
  const int l = lane & 31;                         // lane within row
  const int wid = blockIdx.x * 4 + (threadIdx.x >> 6);
  if (2 * wid >= batch) return;                    // wave-uniform guard
  const int b = 2 * wid + (lane >> 5);             // lanes 0-31: b0, 32-63: b1

  const int nid = ids[b];                          // < 1e5, 32-bit math ok
  const float4 wv = *(const float4*)(adj_weight + nid * MAXDEG + 4 * l);
  // lwp = log(w) + ln2*log2(ln2), once per b (reused for 25 samples).
  const float lwp0 = __logf(wv.x) + 0.36651292f;
  const float lwp1 = __logf(wv.y) + 0.36651292f;
  const float lwp2 = __logf(wv.z) + 0.36651292f;
  const float lwp3 = __logf(wv.w) + 0.36651292f;

  uint32_t sbase = (uint32_t)b * 128u + (uint32_t)(4 * l);
  const uint32_t sstep = (uint32_t)batch * 128u;

  TailState st = {0u, 0u, 0};

  // Hand-pipelined: 12 double-iterations (8 cipher chains in flight), then 1.
  #pragma unroll 1
  for (int s = 0; s < nsamp - 1; s += 2, sbase += 2 * sstep) {
    // phase 1: all 8 independent threefry chains, straight-line
    const uint32_t A0 = tf_bits(sbase + 0u);
    const uint32_t A1 = tf_bits(sbase + 1u);
    const uint32_t A2 = tf_bits(sbase + 2u);
    const uint32_t A3 = tf_bits(sbase + 3u);
    const uint32_t B0 = tf_bits(sbase + sstep + 0u);
    const uint32_t B1 = tf_bits(sbase + sstep + 1u);
    const uint32_t B2 = tf_bits(sbase + sstep + 2u);
    const uint32_t B3 = tf_bits(sbase + sstep + 3u);
    // phase 2: the two serial tails
    sample_tail(s,     lane, lwp0, lwp1, lwp2, lwp3, A0, A1, A2, A3, st);
    sample_tail(s + 1, lane, lwp0, lwp1, lwp2, lwp3, B0, B1, B2, B3, st);
  }
  {  // final (odd) sample
    const int s = nsamp - 1;
    const uint32_t A0 = tf_bits(sbase + 0u);
    const uint32_t A1 = tf_bits(sbase + 1u);
    const uint32_t A2 = tf_bits(sbase + 2u);
    const uint32_t A3 = tf_bits(sbase + 3u);
    sample_tail(s, lane, lwp0, lwp1, lwp2, lwp3, A0, A1, A2, A3, st);
  }

  // Cold exact resolve of flagged samples (expected ~0 per wave).
  const uint32_t rowbase = (uint32_t)b * 128u + (uint32_t)(4 * l);
  for (uint32_t m = st.flagA | st.flagB; m; m &= m - 1u) {
    const int s = __builtin_ctz(m);
    const int bd = resolve_f64(wv, rowbase + (uint32_t)s * sstep, l);
    const int bdA = __shfl(bd, 0);     // row-A winner (broadcast)
    const int bdB = __shfl(bd, 32);    // row-B winner (broadcast)
    if (((st.flagA >> s) & 1u) && lane == s) st.dAcc = bdA;
    if (((st.flagB >> s) & 1u) && lane == s + 32) st.dAcc = bdB;
  }

  // Epilogue: one coalesced gather + one contiguous store per row.
  if (l < nsamp) {
    out[b * nsamp + l] = adj_info[nid * MAXDEG + st.dAcc];
  }
}

extern "C" void kernel_launch(void* const* d_in, const int* in_sizes, int n_in,
                              void* d_out, int out_size, void* d_ws, size_t ws_size,
                              hipStream_t stream) {
  const float* adj_weight = (const float*)d_in[0];
  const int* adj_info = (const int*)d_in[1];
  const int* ids = (const int*)d_in[2];
  int batch = in_sizes[2];
  int nsamp = out_size / batch;             // 25 (<=32 required by flag masks)
  int waves = (batch + 1) / 2;              // 2 rows (b) per wave
  int blocks = (waves + 3) / 4;             // 4 waves per block
  wns_kernel<<<blocks, 256, 0, stream>>>(adj_weight, adj_info, ids,
                                         (int*)d_out, batch, nsamp);
}